// Round 2
// baseline (941.784 us; speedup 1.0000x reference)
//
#include <hip/hip_runtime.h>
#include <hip/hip_bf16.h>

#define B_DIM 1024
#define H_DIM 2048
#define V_DIM 8192
#define L_DIM 8

typedef __attribute__((ext_vector_type(8))) __bf16 bf16x8;
typedef __attribute__((ext_vector_type(4))) __bf16 bf16x4;
typedef __attribute__((ext_vector_type(4))) float f32x4;
typedef unsigned short u16;

// async 16B/lane global->LDS. LDS dest = wave-uniform base + lane*16.
__device__ __forceinline__ void async_copy16(const void* g, void* l) {
  __builtin_amdgcn_global_load_lds(
      (const unsigned int __attribute__((address_space(1)))*)g,
      (unsigned int __attribute__((address_space(3)))*)l,
      16, 0, 0);
}

// ---------- state fp32 -> bf16 (A operand for layer 0) ----------
__global__ __launch_bounds__(256) void conv_state_kernel(
    const float4* __restrict__ in, bf16x4* __restrict__ out) {
  int i = blockIdx.x * 256 + threadIdx.x;
  float4 v = in[i];
  bf16x4 o;
  o.x = (__bf16)v.x; o.y = (__bf16)v.y; o.z = (__bf16)v.z; o.w = (__bf16)v.w;
  out[i] = o;
}

// ---------- per-layer: hh_l fp32 [K][N] -> hhT bf16 [N][K] ----------
// 64x64 tiles through LDS; grid = 32*32 = 1024 blocks
__global__ __launch_bounds__(256) void hh_transpose_kernel(
    const float* __restrict__ hh_l, __bf16* __restrict__ hhT) {
  int t = blockIdx.x;
  int k0 = (t >> 5) << 6;
  int n0 = (t & 31) << 6;
  __shared__ __bf16 tile[64][67];
  int tid = threadIdx.x;
  {
    int r = tid >> 2;               // 0..63
    int c = (tid & 3) << 4;         // 0,16,32,48
    const float4* src = (const float4*)(hh_l + (size_t)(k0 + r) * H_DIM + n0 + c);
#pragma unroll
    for (int q = 0; q < 4; q++) {
      float4 v = src[q];
      tile[r][c + q * 4 + 0] = (__bf16)v.x;
      tile[r][c + q * 4 + 1] = (__bf16)v.y;
      tile[r][c + q * 4 + 2] = (__bf16)v.z;
      tile[r][c + q * 4 + 3] = (__bf16)v.w;
    }
  }
  __syncthreads();
  {
    int n = tid >> 2;               // 0..63
    int kq = (tid & 3) << 4;        // 0,16,32,48
    alignas(16) u16 tmp[16];
#pragma unroll
    for (int j = 0; j < 16; j++) {
      __bf16 b = tile[kq + j][n];
      tmp[j] = *(const u16*)&b;
    }
    uint4* dst = (uint4*)(hhT + (size_t)(n0 + n) * H_DIM + k0 + kq);
    dst[0] = *(uint4*)(tmp);
    dst[1] = *(uint4*)(tmp + 8);
  }
}

// ---------- per-layer fused GEMM + gather + tanh ----------
// C[b][h] = tanh(S[b][h] + (A @ hh_l)[b][h] * ih_l[token[b]][h])
// A: bf16 [1024][2048] (k-contig), Bt: bf16 hhT [n][k] (k-contig)
// S: fp32 residual. Out: fp32 (+ bf16 copy for next layer's A operand)
// BM=BN=BK=64, 256 threads = 2x2 waves, 32x32 per wave
__global__ __launch_bounds__(256) void rnn_layer_kernel(
    const __bf16* __restrict__ A, const __bf16* __restrict__ Bt,
    const float* __restrict__ S, const float* __restrict__ ih_l,
    const int* __restrict__ token,
    float* __restrict__ OutF, __bf16* __restrict__ OutB) {
  constexpr int K = H_DIM;
  __shared__ __align__(16) __bf16 As[64 * 64];
  __shared__ __align__(16) __bf16 Bs[64 * 64];

  // XCD swizzle: the 16 m-blocks sharing an n-column land on one XCD
  int bid = blockIdx.x;
  int x = bid & 7;
  int rest = bid >> 3;
  int mi = rest & 15;
  int ni = (rest >> 4) * 8 + x;
  int bm0 = mi * 64;
  int bn0 = ni * 64;

  int tid = threadIdx.x;
  int w = tid >> 6;
  int lane = tid & 63;
  int rsub = lane >> 3;            // row within 8-row slot
  int csw = (lane & 7) ^ rsub;     // XOR-swizzled source chunk (16B units)

  // LDS phys chunk p at within-slot row r holds logical chunk p ^ r
  const __bf16* pA0 = A + (size_t)(bm0 + (w * 2 + 0) * 8 + rsub) * K + csw * 8;
  const __bf16* pA1 = A + (size_t)(bm0 + (w * 2 + 1) * 8 + rsub) * K + csw * 8;
  const __bf16* pB0 = Bt + (size_t)(bn0 + (w * 2 + 0) * 8 + rsub) * K + csw * 8;
  const __bf16* pB1 = Bt + (size_t)(bn0 + (w * 2 + 1) * 8 + rsub) * K + csw * 8;
  __bf16* lA0 = As + (w * 2 + 0) * 512;
  __bf16* lA1 = As + (w * 2 + 1) * 512;
  __bf16* lB0 = Bs + (w * 2 + 0) * 512;
  __bf16* lB1 = Bs + (w * 2 + 1) * 512;

  int wm = (w >> 1) * 32;
  int wn = (w & 1) * 32;
  int col = lane & 15;
  int quad = lane >> 4;
  int c7 = lane & 7;

  f32x4 acc[2][2] = {};

  for (int kt = 0; kt < K; kt += 64) {
    __syncthreads();
    async_copy16(pA0 + kt, lA0);
    async_copy16(pA1 + kt, lA1);
    async_copy16(pB0 + kt, lB0);
    async_copy16(pB1 + kt, lB1);
    __syncthreads();   // compiler emits vmcnt(0) drain before barrier
#pragma unroll
    for (int ks = 0; ks < 2; ks++) {
      int cc = ks * 4 + quad;       // logical 16B chunk (k = cc*8 .. +7)
      bf16x8 a0 = *(const bf16x8*)(As + (wm + 0 + col) * 64 + ((cc ^ c7) * 8));
      bf16x8 a1 = *(const bf16x8*)(As + (wm + 16 + col) * 64 + ((cc ^ c7) * 8));
      bf16x8 b0 = *(const bf16x8*)(Bs + (wn + 0 + col) * 64 + ((cc ^ c7) * 8));
      bf16x8 b1 = *(const bf16x8*)(Bs + (wn + 16 + col) * 64 + ((cc ^ c7) * 8));
      acc[0][0] = __builtin_amdgcn_mfma_f32_16x16x32_bf16(a0, b0, acc[0][0], 0, 0, 0);
      acc[0][1] = __builtin_amdgcn_mfma_f32_16x16x32_bf16(a0, b1, acc[0][1], 0, 0, 0);
      acc[1][0] = __builtin_amdgcn_mfma_f32_16x16x32_bf16(a1, b0, acc[1][0], 0, 0, 0);
      acc[1][1] = __builtin_amdgcn_mfma_f32_16x16x32_bf16(a1, b1, acc[1][1], 0, 0, 0);
    }
  }

  // epilogue: C/D layout col=lane&15, row=quad*4+reg
#pragma unroll
  for (int mt = 0; mt < 2; mt++) {
#pragma unroll
    for (int reg = 0; reg < 4; reg++) {
      int b = bm0 + wm + mt * 16 + quad * 4 + reg;
      int tok = token[b];
      const float* ihrow = ih_l + (size_t)tok * H_DIM;
      size_t rowoff = (size_t)b * H_DIM;
#pragma unroll
      for (int nt = 0; nt < 2; nt++) {
        int h = bn0 + wn + nt * 16 + col;
        float g = ihrow[h];
        float sv = S[rowoff + h];
        float v = tanhf(fmaf(acc[mt][nt][reg], g, sv));
        OutF[rowoff + h] = v;
        OutB[rowoff + h] = (__bf16)v;
      }
    }
  }
}

extern "C" void kernel_launch(void* const* d_in, const int* in_sizes, int n_in,
                              void* d_out, int out_size, void* d_ws, size_t ws_size,
                              hipStream_t stream) {
  const float* state = (const float*)d_in[0];
  const int* token = (const int*)d_in[1];
  const float* ih = (const float*)d_in[2];
  const float* hh = (const float*)d_in[3];

  // ws layout (32 MiB total):
  char* ws = (char*)d_ws;
  __bf16* hhT = (__bf16*)ws;                  // 2048*2048*2 = 8388608 B (reused per layer)
  float* F0 = (float*)(ws + 8388608);         // 8388608 B
  float* F1 = (float*)(ws + 16777216);        // 8388608 B
  __bf16* Sb0 = (__bf16*)(ws + 25165824);     // 4194304 B
  __bf16* Sb1 = (__bf16*)(ws + 29360128);     // 4194304 B

  // state -> bf16 A operand for layer 0
  conv_state_kernel<<<2048, 256, 0, stream>>>((const float4*)state, (bf16x4*)Sb0);

  const float* Sprev = state;                 // fp32 residual
  for (int l = 0; l < L_DIM; l++) {
    const float* hh_l = hh + ((size_t)l << 22);       // l * 2048*2048
    const float* ih_l = ih + ((size_t)l << 24);       // l * 8192*2048
    hh_transpose_kernel<<<1024, 256, 0, stream>>>(hh_l, hhT);

    const __bf16* Acur = (l & 1) ? Sb1 : Sb0;
    __bf16* outB = (l & 1) ? Sb0 : Sb1;
    float* outF = (l == L_DIM - 1) ? (float*)d_out : ((l & 1) ? F1 : F0);
    rnn_layer_kernel<<<512, 256, 0, stream>>>(Acur, hhT, Sprev, ih_l, token, outF, outB);
    Sprev = outF;
  }
}

// Round 3
// 924.277 us; speedup vs baseline: 1.0189x; 1.0189x over previous
//
#include <hip/hip_runtime.h>
#include <hip/hip_bf16.h>

#define B_DIM 1024
#define H_DIM 2048
#define V_DIM 8192
#define L_DIM 8

typedef __attribute__((ext_vector_type(8))) __bf16 bf16x8;
typedef __attribute__((ext_vector_type(4))) __bf16 bf16x4;
typedef __attribute__((ext_vector_type(4))) float f32x4;
typedef unsigned short u16;

#define ASM_BARRIER() asm volatile("s_barrier" ::: "memory")
#define WAIT_VM4() asm volatile("s_waitcnt vmcnt(4)" ::: "memory")
#define WAIT_VM0() asm volatile("s_waitcnt vmcnt(0)" ::: "memory")

// async 16B/lane global->LDS. LDS dest = wave-uniform base + lane*16.
__device__ __forceinline__ void async_copy16(const void* g, void* l) {
  __builtin_amdgcn_global_load_lds(
      (const unsigned int __attribute__((address_space(1)))*)g,
      (unsigned int __attribute__((address_space(3)))*)l,
      16, 0, 0);
}

// ---------- state fp32 -> bf16 (A operand for layer 0) ----------
__global__ __launch_bounds__(256) void rnn_conv_state(
    const float4* __restrict__ in, bf16x4* __restrict__ out) {
  int i = blockIdx.x * 256 + threadIdx.x;
  float4 v = in[i];
  bf16x4 o;
  o.x = (__bf16)v.x; o.y = (__bf16)v.y; o.z = (__bf16)v.z; o.w = (__bf16)v.w;
  out[i] = o;
}

// ---------- ALL layers: hh fp32 [L][K][N] -> hhT bf16 [L][N][K] ----------
// 64x64 tiles through LDS; grid = 8 * 32 * 32 = 8192 blocks (one dispatch)
__global__ __launch_bounds__(256) void rnn_hh_transpose_all(
    const float* __restrict__ hh, __bf16* __restrict__ hhT) {
  int bid = blockIdx.x;
  int l = bid >> 10;
  int t = bid & 1023;
  int k0 = (t >> 5) << 6;
  int n0 = (t & 31) << 6;
  __shared__ __bf16 tile[64][67];
  int tid = threadIdx.x;
  const float* hh_l = hh + ((size_t)l << 22);
  __bf16* hhT_l = hhT + ((size_t)l << 22);
  {
    int r = tid >> 2;               // 0..63
    int c = (tid & 3) << 4;         // 0,16,32,48
    const float4* src = (const float4*)(hh_l + (size_t)(k0 + r) * H_DIM + n0 + c);
#pragma unroll
    for (int q = 0; q < 4; q++) {
      float4 v = src[q];
      tile[r][c + q * 4 + 0] = (__bf16)v.x;
      tile[r][c + q * 4 + 1] = (__bf16)v.y;
      tile[r][c + q * 4 + 2] = (__bf16)v.z;
      tile[r][c + q * 4 + 3] = (__bf16)v.w;
    }
  }
  __syncthreads();
  {
    int n = tid >> 2;               // 0..63
    int kq = (tid & 3) << 4;        // 0,16,32,48
    alignas(16) u16 tmp[16];
#pragma unroll
    for (int j = 0; j < 16; j++) {
      __bf16 b = tile[kq + j][n];
      tmp[j] = *(const u16*)&b;
    }
    uint4* dst = (uint4*)(hhT_l + (size_t)(n0 + n) * H_DIM + k0 + kq);
    dst[0] = *(uint4*)(tmp);
    dst[1] = *(uint4*)(tmp + 8);
  }
}

// ---------- per-layer fused GEMM + gather + tanh, software-pipelined ----------
// C[b][h] = tanh(S[b][h] + (A @ hh_l)[b][h] * ih_l[token[b]][h])
// Double-buffered LDS; raw s_barrier + s_waitcnt vmcnt(4) keeps next tile's
// global_load_lds in flight across the barrier (break the vmcnt(0) drain).
__global__ __launch_bounds__(256) void rnn_layer_pipe(
    const __bf16* __restrict__ A, const __bf16* __restrict__ Bt,
    const float* __restrict__ S, const float* __restrict__ ih_l,
    const int* __restrict__ token,
    float* __restrict__ OutF, __bf16* __restrict__ OutB) {
  constexpr int K = H_DIM;
  constexpr int NT = K / 64;       // 32 K-tiles
  __shared__ __align__(16) __bf16 As[2][64 * 64];
  __shared__ __align__(16) __bf16 Bs[2][64 * 64];

  // XCD swizzle: the 16 m-blocks sharing an n-column land on one XCD
  int bid = blockIdx.x;
  int x = bid & 7;
  int rest = bid >> 3;
  int mi = rest & 15;
  int ni = (rest >> 4) * 8 + x;
  int bm0 = mi * 64;
  int bn0 = ni * 64;

  int tid = threadIdx.x;
  int w = tid >> 6;
  int lane = tid & 63;
  int rsub = lane >> 3;            // row within 8-row slot
  int csw = (lane & 7) ^ rsub;     // XOR-swizzled source chunk (16B units)

  // LDS phys chunk p at within-slot row r holds logical chunk p ^ r
  const __bf16* pA0 = A + (size_t)(bm0 + (w * 2 + 0) * 8 + rsub) * K + csw * 8;
  const __bf16* pA1 = A + (size_t)(bm0 + (w * 2 + 1) * 8 + rsub) * K + csw * 8;
  const __bf16* pB0 = Bt + (size_t)(bn0 + (w * 2 + 0) * 8 + rsub) * K + csw * 8;
  const __bf16* pB1 = Bt + (size_t)(bn0 + (w * 2 + 1) * 8 + rsub) * K + csw * 8;
  int slot0 = (w * 2 + 0) * 512;
  int slot1 = (w * 2 + 1) * 512;

  int wm = (w >> 1) * 32;
  int wn = (w & 1) * 32;
  int col = lane & 15;
  int quad = lane >> 4;
  int c7 = lane & 7;

  f32x4 acc[2][2] = {};

  auto issue = [&](int buf, int kt) {
    int ko = kt * 64;
    async_copy16(pA0 + ko, &As[buf][slot0]);
    async_copy16(pA1 + ko, &As[buf][slot1]);
    async_copy16(pB0 + ko, &Bs[buf][slot0]);
    async_copy16(pB1 + ko, &Bs[buf][slot1]);
  };
  auto compute = [&](int buf) {
#pragma unroll
    for (int ks = 0; ks < 2; ks++) {
      int cc = ks * 4 + quad;       // logical 16B chunk (k = cc*8 .. +7)
      bf16x8 a0 = *(const bf16x8*)(&As[buf][(wm + 0 + col) * 64 + ((cc ^ c7) * 8)]);
      bf16x8 a1 = *(const bf16x8*)(&As[buf][(wm + 16 + col) * 64 + ((cc ^ c7) * 8)]);
      bf16x8 b0 = *(const bf16x8*)(&Bs[buf][(wn + 0 + col) * 64 + ((cc ^ c7) * 8)]);
      bf16x8 b1 = *(const bf16x8*)(&Bs[buf][(wn + 16 + col) * 64 + ((cc ^ c7) * 8)]);
      acc[0][0] = __builtin_amdgcn_mfma_f32_16x16x32_bf16(a0, b0, acc[0][0], 0, 0, 0);
      acc[0][1] = __builtin_amdgcn_mfma_f32_16x16x32_bf16(a0, b1, acc[0][1], 0, 0, 0);
      acc[1][0] = __builtin_amdgcn_mfma_f32_16x16x32_bf16(a1, b0, acc[1][0], 0, 0, 0);
      acc[1][1] = __builtin_amdgcn_mfma_f32_16x16x32_bf16(a1, b1, acc[1][1], 0, 0, 0);
    }
  };

  issue(0, 0);
  for (int kt = 0; kt < NT; kt += 2) {
    // even phase: compute tile kt from buf0, tile kt+1 in flight to buf1
    issue(1, kt + 1);
    WAIT_VM4();         // my 4 tile-kt copies done; tile-(kt+1) still in flight
    ASM_BARRIER();      // all waves' tile-kt data now in LDS
    compute(0);
    ASM_BARRIER();      // all waves done reading buf0 -> safe to overwrite
    // odd phase: compute tile kt+1 from buf1
    if (kt + 2 < NT) {
      issue(0, kt + 2);
      WAIT_VM4();
    } else {
      WAIT_VM0();
    }
    ASM_BARRIER();
    compute(1);
    ASM_BARRIER();
  }

  // epilogue: C/D layout col=lane&15, row=quad*4+reg
#pragma unroll
  for (int mt = 0; mt < 2; mt++) {
#pragma unroll
    for (int reg = 0; reg < 4; reg++) {
      int b = bm0 + wm + mt * 16 + quad * 4 + reg;
      int tok = token[b];
      const float* ihrow = ih_l + (size_t)tok * H_DIM;
      size_t rowoff = (size_t)b * H_DIM;
#pragma unroll
      for (int nt = 0; nt < 2; nt++) {
        int h = bn0 + wn + nt * 16 + col;
        float g = ihrow[h];
        float sv = S[rowoff + h];
        float v = tanhf(fmaf(acc[mt][nt][reg], g, sv));
        OutF[rowoff + h] = v;
        OutB[rowoff + h] = (__bf16)v;
      }
    }
  }
}

extern "C" void kernel_launch(void* const* d_in, const int* in_sizes, int n_in,
                              void* d_out, int out_size, void* d_ws, size_t ws_size,
                              hipStream_t stream) {
  const float* state = (const float*)d_in[0];
  const int* token = (const int*)d_in[1];
  const float* ih = (const float*)d_in[2];
  const float* hh = (const float*)d_in[3];

  // ws layout (88 MiB used):
  char* ws = (char*)d_ws;
  __bf16* hhT = (__bf16*)ws;                    // 8*2048*2048*2 = 67108864 B
  float* F0 = (float*)(ws + 67108864);          // 8388608 B
  float* F1 = (float*)(ws + 75497472);          // 8388608 B
  __bf16* Sb0 = (__bf16*)(ws + 83886080);       // 4194304 B
  __bf16* Sb1 = (__bf16*)(ws + 88080384);       // 4194304 B

  // all-layer weight transpose (independent of the RNN chain) + state convert
  rnn_hh_transpose_all<<<8192, 256, 0, stream>>>(hh, hhT);
  rnn_conv_state<<<2048, 256, 0, stream>>>((const float4*)state, (bf16x4*)Sb0);

  const float* Sprev = state;                   // fp32 residual
  for (int l = 0; l < L_DIM; l++) {
    const __bf16* hhT_l = hhT + ((size_t)l << 22);
    const float* ih_l = ih + ((size_t)l << 24);
    const __bf16* Acur = (l & 1) ? Sb1 : Sb0;
    __bf16* outB = (l & 1) ? Sb0 : Sb1;
    float* outF = (l == L_DIM - 1) ? (float*)d_out : ((l & 1) ? F1 : F0);
    rnn_layer_pipe<<<512, 256, 0, stream>>>(Acur, hhT_l, Sprev, ih_l, token, outF, outB);
    Sprev = outF;
  }
}